// Round 5
// baseline (74.046 us; speedup 1.0000x reference)
//
#include <hip/hip_runtime.h>

#define N 4096
#define D 1024
#define EPSF 1e-6f

typedef _Float16 f16;
typedef f16 f16x8 __attribute__((ext_vector_type(8)));
typedef f16 f16x4 __attribute__((ext_vector_type(4)));
typedef float f32x4 __attribute__((ext_vector_type(4)));
typedef unsigned long long u64;

struct WS {
  int n_A, mid, n2, n_B, n_resid, pad[3];
  float a[N];
  int A1idx[N];
  int A2idx[N];
  int Bidx[N];
  int matches[N];
  int residIdx[N];
  u64 bestKey[2048];
};

__device__ __forceinline__ u64 packKey(float v, int j) {
  unsigned u = __float_as_uint(v);
  unsigned m = (u & 0x80000000u) ? ~u : (u | 0x80000000u);
  return ((u64)m << 32) | (unsigned)(~(unsigned)j);
}

// row means + planar f16 hi/lo split of x (into d_out scratch)
__global__ __launch_bounds__(256) void k_prep(const float* __restrict__ x,
                                              f16* __restrict__ hi,
                                              f16* __restrict__ lo, WS* ws) {
  int row = blockIdx.x;
  int t = threadIdx.x;
  float4 v = ((const float4*)(x + (size_t)row * D))[t];
  float vv[4] = {v.x, v.y, v.z, v.w};
  f16x4 h, l;
  #pragma unroll
  for (int q = 0; q < 4; q++) {
    f16 hq = (f16)vv[q];
    h[q] = hq;
    l[q] = (f16)(vv[q] - (float)hq);
  }
  *(f16x4*)(hi + (size_t)row * D + t * 4) = h;
  *(f16x4*)(lo + (size_t)row * D + t * 4) = l;
  float sm = v.x + v.y + v.z + v.w;
  for (int o = 32; o; o >>= 1) sm += __shfl_down(sm, o, 64);
  __shared__ float w[4];
  if ((t & 63) == 0) w[t >> 6] = sm;
  __syncthreads();
  if (t == 0) ws->a[row] = (w[0] + w[1] + w[2] + w[3]) * (1.0f / D);
}

// fused: stats(a) -> z -> Il -> stats(Il) -> s -> radix-select median(|s|)
//        -> mask + stable compaction + bestKey zero-init
__global__ __launch_bounds__(1024) void k_mask(const float* __restrict__ attn, WS* ws) {
  __shared__ double dred[16], dred2[16];
  __shared__ float bcast[2];
  __shared__ int hist[256];
  __shared__ int wsum[16];
  __shared__ unsigned sPrefix;
  __shared__ int sRank;
  int tid = threadIdx.x;
  int lane = tid & 63, wv = tid >> 6;

  ws->bestKey[tid] = 0ull;
  ws->bestKey[tid + 1024] = 0ull;

  // --- stats of a ---
  float av[4];
  double s = 0.0, s2 = 0.0;
  #pragma unroll
  for (int q = 0; q < 4; q++) {
    float f = ws->a[tid * 4 + q];
    av[q] = f; s += f; s2 += (double)f * f;
  }
  for (int o = 32; o; o >>= 1) { s += __shfl_down(s, o, 64); s2 += __shfl_down(s2, o, 64); }
  if (lane == 0) { dred[wv] = s; dred2[wv] = s2; }
  __syncthreads();
  if (tid == 0) {
    double t1 = 0, t2 = 0;
    for (int i = 0; i < 16; i++) { t1 += dred[i]; t2 += dred2[i]; }
    bcast[0] = (float)(t1 / N);
    bcast[1] = (float)sqrt((t2 - t1 * t1 / N) / (N - 1));
  }
  __syncthreads();
  float meanA = bcast[0], stdA = bcast[1];

  // --- Il = z^2 * diag(attn), plus its stats ---
  float il[4];
  s = 0.0; s2 = 0.0;
  #pragma unroll
  for (int q = 0; q < 4; q++) {
    int i = tid * 4 + q;
    float z = (av[q] - meanA) / (stdA + EPSF);
    float I = z * z * attn[(size_t)i * N + i];
    il[q] = I; s += I; s2 += (double)I * I;
  }
  for (int o = 32; o; o >>= 1) { s += __shfl_down(s, o, 64); s2 += __shfl_down(s2, o, 64); }
  __syncthreads();
  if (lane == 0) { dred[wv] = s; dred2[wv] = s2; }
  __syncthreads();
  if (tid == 0) {
    double t1 = 0, t2 = 0;
    for (int i = 0; i < 16; i++) { t1 += dred[i]; t2 += dred2[i]; }
    bcast[0] = (float)(t1 / N);
    bcast[1] = (float)sqrt((t2 - t1 * t1 / N) / (N - 1));
    sPrefix = 0u; sRank = (N - 1) / 2;
  }
  __syncthreads();
  float meanI = bcast[0], stdI = bcast[1];

  float sv[4]; unsigned ab[4];
  #pragma unroll
  for (int q = 0; q < 4; q++) {
    float sval = (il[q] - meanI) / (stdI + EPSF);
    sv[q] = sval;
    ab[q] = __float_as_uint(fabsf(sval));
  }

  // --- radix select rank-2047 of |s| bit patterns (parallel bucket find) ---
  for (int p = 3; p >= 0; p--) {
    if (tid < 256) hist[tid] = 0;
    __syncthreads();
    unsigned pre = sPrefix;
    int rk = sRank;
    int sh = p * 8;
    unsigned mHi = (p == 3) ? 0u : (0xFFFFFFFFu << (sh + 8));
    #pragma unroll
    for (int q = 0; q < 4; q++)
      if ((ab[q] & mHi) == pre) atomicAdd(&hist[(ab[q] >> sh) & 255], 1);
    __syncthreads();
    int v = (tid < 256) ? hist[tid] : 0;
    int inc = v;
    #pragma unroll
    for (int o = 1; o < 64; o <<= 1) { int u = __shfl_up(inc, o, 64); if (lane >= o) inc += u; }
    if (lane == 63) wsum[wv] = inc;
    __syncthreads();
    if (tid < 16) {
      int t = wsum[tid];
      #pragma unroll
      for (int o = 1; o < 16; o <<= 1) { int u = __shfl_up(t, o, 64); if (tid >= o) t += u; }
      wsum[tid] = t;
    }
    __syncthreads();
    int incl = (wv ? wsum[wv - 1] : 0) + inc;
    int E = incl - v;
    if (tid < 256 && v && rk >= E && rk < E + v) {
      sPrefix = pre | ((unsigned)tid << sh);
      sRank = rk - E;
    }
    __syncthreads();
  }
  float med = __uint_as_float(sPrefix);

  // --- mask (strict |s| > med, bit-exact) + stable compaction (wave scan) ---
  int msk[4], loc[4]; int tot = 0;
  #pragma unroll
  for (int q = 0; q < 4; q++) {
    bool m = fabsf(sv[q]) > med;
    msk[q] = m; loc[q] = tot; tot += (int)m;
  }
  int inc = tot;
  #pragma unroll
  for (int o = 1; o < 64; o <<= 1) { int u = __shfl_up(inc, o, 64); if (lane >= o) inc += u; }
  if (lane == 63) wsum[wv] = inc;
  __syncthreads();
  if (tid < 16) {
    int t = wsum[tid];
    #pragma unroll
    for (int o = 1; o < 16; o <<= 1) { int u = __shfl_up(t, o, 64); if (tid >= o) t += u; }
    wsum[tid] = t;
  }
  __syncthreads();
  int nA = wsum[15];
  int base = (wv ? wsum[wv - 1] : 0) + inc - tot;
  int midl = nA >> 1;
  #pragma unroll
  for (int q = 0; q < 4; q++) {
    int i = tid * 4 + q;
    int r = base + loc[q];
    if (msk[q]) {
      if (r < midl) ws->A1idx[r] = i; else ws->A2idx[r - midl] = i;
    } else {
      ws->Bidx[i - r] = i;
    }
  }
  if (tid == 0) { ws->n_A = nA; ws->mid = midl; ws->n2 = nA - midl; ws->n_B = N - nA; }
}

// f16x3 MFMA sim + per-row argmax. One 32x32 tile per 128-thr block; the two
// waves split K (512 each); fragments loaded straight from global hi/lo planes
// (per-lane row base + immediate offsets, no LDS staging, no barriers in loop).
__global__ __launch_bounds__(128) void k_gemm(const f16* __restrict__ hi,
                                              const f16* __restrict__ lo, WS* ws) {
  const int mid = ws->mid, n2 = ws->n2;
  // XCD-aware remap: xcd L&7 owns bj strip [xcd*4, xcd*4+4) -> B stays in its L2
  int L = blockIdx.x;
  int local = L >> 3;
  int bj = ((L & 7) << 2) | (local >> 5);
  int bi = local & 31;
  if (bi * 32 >= mid || bj * 32 >= n2) return;

  __shared__ float comb[64][17];  // +1 pad: conflict-free K-half combine

  const int tid = threadIdx.x;
  const int w = tid >> 6;       // K-half
  const int lane = tid & 63;
  const int colg = lane & 15, rowg = lane >> 4;

  int ar0 = bi * 32 + colg;      if (ar0 > mid - 1) ar0 = mid - 1;
  int ar1 = ar0 + 16;            if (ar1 > mid - 1) ar1 = mid - 1;
  int br0 = bj * 32 + colg;      if (br0 > n2 - 1) br0 = n2 - 1;
  int br1 = br0 + 16;            if (br1 > n2 - 1) br1 = n2 - 1;
  const size_t off = (size_t)w * 1024 + rowg * 16;  // byte offset within row
  const char* pAh0 = (const char*)hi + (size_t)ws->A1idx[ar0] * 2048 + off;
  const char* pAh1 = (const char*)hi + (size_t)ws->A1idx[ar1] * 2048 + off;
  const char* pAl0 = (const char*)lo + (size_t)ws->A1idx[ar0] * 2048 + off;
  const char* pAl1 = (const char*)lo + (size_t)ws->A1idx[ar1] * 2048 + off;
  const char* pBh0 = (const char*)hi + (size_t)ws->A2idx[br0] * 2048 + off;
  const char* pBh1 = (const char*)hi + (size_t)ws->A2idx[br1] * 2048 + off;
  const char* pBl0 = (const char*)lo + (size_t)ws->A2idx[br0] * 2048 + off;
  const char* pBl1 = (const char*)lo + (size_t)ws->A2idx[br1] * 2048 + off;

  f32x4 zero = {0.f, 0.f, 0.f, 0.f};
  f32x4 hh[2][2], hl[2][2], lh[2][2];  // 12 independent accumulator chains
  #pragma unroll
  for (int i = 0; i < 2; i++)
    #pragma unroll
    for (int j = 0; j < 2; j++) { hh[i][j] = zero; hl[i][j] = zero; lh[i][j] = zero; }

  #pragma unroll
  for (int t = 0; t < 16; t++) {
    const int o = t * 64;  // 32 f16 per K-chunk
    f16x8 ah0 = *(const f16x8*)(pAh0 + o);
    f16x8 ah1 = *(const f16x8*)(pAh1 + o);
    f16x8 al0 = *(const f16x8*)(pAl0 + o);
    f16x8 al1 = *(const f16x8*)(pAl1 + o);
    f16x8 bh0 = *(const f16x8*)(pBh0 + o);
    f16x8 bh1 = *(const f16x8*)(pBh1 + o);
    f16x8 bl0 = *(const f16x8*)(pBl0 + o);
    f16x8 bl1 = *(const f16x8*)(pBl1 + o);
    hh[0][0] = __builtin_amdgcn_mfma_f32_16x16x32_f16(ah0, bh0, hh[0][0], 0, 0, 0);
    hh[0][1] = __builtin_amdgcn_mfma_f32_16x16x32_f16(ah0, bh1, hh[0][1], 0, 0, 0);
    hh[1][0] = __builtin_amdgcn_mfma_f32_16x16x32_f16(ah1, bh0, hh[1][0], 0, 0, 0);
    hh[1][1] = __builtin_amdgcn_mfma_f32_16x16x32_f16(ah1, bh1, hh[1][1], 0, 0, 0);
    hl[0][0] = __builtin_amdgcn_mfma_f32_16x16x32_f16(ah0, bl0, hl[0][0], 0, 0, 0);
    hl[0][1] = __builtin_amdgcn_mfma_f32_16x16x32_f16(ah0, bl1, hl[0][1], 0, 0, 0);
    hl[1][0] = __builtin_amdgcn_mfma_f32_16x16x32_f16(ah1, bl0, hl[1][0], 0, 0, 0);
    hl[1][1] = __builtin_amdgcn_mfma_f32_16x16x32_f16(ah1, bl1, hl[1][1], 0, 0, 0);
    lh[0][0] = __builtin_amdgcn_mfma_f32_16x16x32_f16(al0, bh0, lh[0][0], 0, 0, 0);
    lh[0][1] = __builtin_amdgcn_mfma_f32_16x16x32_f16(al0, bh1, lh[0][1], 0, 0, 0);
    lh[1][0] = __builtin_amdgcn_mfma_f32_16x16x32_f16(al1, bh0, lh[1][0], 0, 0, 0);
    lh[1][1] = __builtin_amdgcn_mfma_f32_16x16x32_f16(al1, bh1, lh[1][1], 0, 0, 0);
  }

  f32x4 s[2][2];
  #pragma unroll
  for (int i = 0; i < 2; i++)
    #pragma unroll
    for (int j = 0; j < 2; j++) s[i][j] = (hh[i][j] + hl[i][j]) + lh[i][j];

  if (w == 1) {
    #pragma unroll
    for (int i = 0; i < 2; i++)
      #pragma unroll
      for (int j = 0; j < 2; j++)
        #pragma unroll
        for (int r = 0; r < 4; r++) comb[lane][i * 8 + j * 4 + r] = s[i][j][r];
  }
  __syncthreads();
  if (w == 0) {
    #pragma unroll
    for (int i = 0; i < 2; i++)
      #pragma unroll
      for (int j = 0; j < 2; j++)
        #pragma unroll
        for (int r = 0; r < 4; r++) s[i][j][r] += comb[lane][i * 8 + j * 4 + r];
    // argmax epilogue: C layout col=lane&15, row=(lane>>4)*4+reg
    #pragma unroll
    for (int mi = 0; mi < 2; mi++) {
      #pragma unroll
      for (int r = 0; r < 4; r++) {
        int grow = bi * 32 + mi * 16 + rowg * 4 + r;
        u64 key = 0;
        #pragma unroll
        for (int ni = 0; ni < 2; ni++) {
          int gcol = bj * 32 + ni * 16 + colg;
          if (gcol < n2) {
            u64 k2 = packKey(s[mi][ni][r], gcol);
            if (k2 > key) key = k2;
          }
        }
        #pragma unroll
        for (int m = 8; m; m >>= 1) {
          u64 o = (u64)__shfl_xor((long long)key, m, 64);
          if (o > key) key = o;
        }
        if (colg == 0 && grow < mid && key) atomicMax(&ws->bestKey[grow], key);
      }
    }
  }
}

// decode matches + residual compaction (fused, single block, wave scan)
__global__ __launch_bounds__(1024) void k_match(WS* ws) {
  __shared__ int flag[N];
  __shared__ int wsum[16];
  int tid = threadIdx.x;
  int lane = tid & 63, wv = tid >> 6;
  int mid = ws->mid, n2 = ws->n2;
  #pragma unroll
  for (int q = 0; q < 4; q++) flag[tid * 4 + q] = 0;
  __syncthreads();
  #pragma unroll
  for (int q = 0; q < 2; q++) {
    int r = tid + q * 1024;
    if (r < mid) {
      int j = (int)(~(unsigned)(ws->bestKey[r] & 0xffffffffull));
      ws->matches[r] = j;
      flag[j] = 1;  // benign race: same value
    }
  }
  __syncthreads();
  int v[4], loc[4]; int tot = 0;
  #pragma unroll
  for (int q = 0; q < 4; q++) {
    int j = tid * 4 + q;
    bool val = (j < n2) && (flag[j] == 0);
    v[q] = val; loc[q] = tot; tot += (int)val;
  }
  int inc = tot;
  #pragma unroll
  for (int o = 1; o < 64; o <<= 1) { int u = __shfl_up(inc, o, 64); if (lane >= o) inc += u; }
  if (lane == 63) wsum[wv] = inc;
  __syncthreads();
  if (tid < 16) {
    int t = wsum[tid];
    #pragma unroll
    for (int o = 1; o < 16; o <<= 1) { int u = __shfl_up(t, o, 64); if (tid >= o) t += u; }
    wsum[tid] = t;
  }
  __syncthreads();
  int base = (wv ? wsum[wv - 1] : 0) + inc - tot;
  #pragma unroll
  for (int q = 0; q < 4; q++)
    if (v[q]) ws->residIdx[base + loc[q]] = ws->A2idx[tid * 4 + q];
  if (tid == 0) ws->n_resid = wsum[15];
}

// one block per output row (out rows [0,N), residual rows [N,2N))
__global__ __launch_bounds__(256) void k_write(const float* __restrict__ x,
                                               float* __restrict__ out, WS* ws) {
  int r = blockIdx.x;
  int t = threadIdx.x;
  int n_B = ws->n_B, mid = ws->mid, n_resid = ws->n_resid;
  float4 res = make_float4(0.f, 0.f, 0.f, 0.f);
  if (r < N) {
    if (r < n_B) {
      res = ((const float4*)(x + (size_t)ws->Bidx[r] * D))[t];
    } else if (r < n_B + mid) {
      int m = r - n_B;
      float4 v1 = ((const float4*)(x + (size_t)ws->A1idx[m] * D))[t];
      float4 v2 = ((const float4*)(x + (size_t)ws->A2idx[ws->matches[m]] * D))[t];
      res = make_float4(0.5f * (v1.x + v2.x), 0.5f * (v1.y + v2.y),
                        0.5f * (v1.z + v2.z), 0.5f * (v1.w + v2.w));
    }
  } else {
    int k = r - N;
    if (k < n_resid) {
      res = ((const float4*)(x + (size_t)ws->residIdx[k] * D))[t];
    }
  }
  ((float4*)(out + (size_t)r * D))[t] = res;
}

extern "C" void kernel_launch(void* const* d_in, const int* in_sizes, int n_in,
                              void* d_out, int out_size, void* d_ws, size_t ws_size,
                              hipStream_t stream) {
  const float* x = (const float*)d_in[0];
  const float* attn = (const float*)d_in[1];
  float* out = (float*)d_out;
  WS* ws = (WS*)d_ws;
  // d_out (33.5 MB) doubles as scratch for the planar f16 hi/lo split (16 MB);
  // k_write fully overwrites it afterwards (stream-ordered, deterministic).
  f16* hi = (f16*)d_out;
  f16* lo = hi + (size_t)N * D;

  k_prep<<<N, 256, 0, stream>>>(x, hi, lo, ws);
  k_mask<<<1, 1024, 0, stream>>>(attn, ws);
  k_gemm<<<1024, 128, 0, stream>>>(hi, lo, ws);
  k_match<<<1, 1024, 0, stream>>>(ws);
  k_write<<<2 * N, 256, 0, stream>>>(x, out, ws);
}

// Round 6
// 64.066 us; speedup vs baseline: 1.1558x; 1.1558x over previous
//
#include <hip/hip_runtime.h>

#define N 4096
#define D 1024
#define EPSF 1e-6f

typedef _Float16 f16;
typedef f16 f16x8 __attribute__((ext_vector_type(8)));
typedef f16 f16x4 __attribute__((ext_vector_type(4)));
typedef float f32x4 __attribute__((ext_vector_type(4)));
typedef unsigned long long u64;

struct WS {
  int n_A, mid, n2, n_B, n_resid, pad[3];
  float a[N];
  int A1idx[N];
  int A2idx[N];
  int Bidx[N];
  int matches[N];
  int residIdx[N];
  u64 bestKey[2048];
};

__device__ __forceinline__ u64 packKey(float v, int j) {
  unsigned u = __float_as_uint(v);
  unsigned m = (u & 0x80000000u) ? ~u : (u | 0x80000000u);
  return ((u64)m << 32) | (unsigned)(~(unsigned)j);
}

// row means of x
__global__ __launch_bounds__(256) void k_prep(const float* __restrict__ x, WS* ws) {
  int row = blockIdx.x;
  int t = threadIdx.x;
  float4 v = ((const float4*)(x + (size_t)row * D))[t];
  float sm = v.x + v.y + v.z + v.w;
  for (int o = 32; o; o >>= 1) sm += __shfl_down(sm, o, 64);
  __shared__ float w[4];
  if ((t & 63) == 0) w[t >> 6] = sm;
  __syncthreads();
  if (t == 0) ws->a[row] = (w[0] + w[1] + w[2] + w[3]) * (1.0f / D);
}

// fused: stats(a) -> z -> Il -> stats(Il) -> s -> radix-select median(|s|)
//        -> mask + stable compaction + bestKey zero-init
__global__ __launch_bounds__(1024) void k_mask(const float* __restrict__ attn, WS* ws) {
  __shared__ double dred[16], dred2[16];
  __shared__ float bcast[2];
  __shared__ int hist[256];
  __shared__ int wsum[16];
  __shared__ unsigned sPrefix;
  __shared__ int sRank;
  int tid = threadIdx.x;
  int lane = tid & 63, wv = tid >> 6;

  ws->bestKey[tid] = 0ull;
  ws->bestKey[tid + 1024] = 0ull;

  // --- stats of a ---
  float av[4];
  double s = 0.0, s2 = 0.0;
  #pragma unroll
  for (int q = 0; q < 4; q++) {
    float f = ws->a[tid * 4 + q];
    av[q] = f; s += f; s2 += (double)f * f;
  }
  for (int o = 32; o; o >>= 1) { s += __shfl_down(s, o, 64); s2 += __shfl_down(s2, o, 64); }
  if (lane == 0) { dred[wv] = s; dred2[wv] = s2; }
  __syncthreads();
  if (tid == 0) {
    double t1 = 0, t2 = 0;
    for (int i = 0; i < 16; i++) { t1 += dred[i]; t2 += dred2[i]; }
    bcast[0] = (float)(t1 / N);
    bcast[1] = (float)sqrt((t2 - t1 * t1 / N) / (N - 1));
  }
  __syncthreads();
  float meanA = bcast[0], stdA = bcast[1];

  // --- Il = z^2 * diag(attn), plus its stats ---
  float il[4];
  s = 0.0; s2 = 0.0;
  #pragma unroll
  for (int q = 0; q < 4; q++) {
    int i = tid * 4 + q;
    float z = (av[q] - meanA) / (stdA + EPSF);
    float I = z * z * attn[(size_t)i * N + i];
    il[q] = I; s += I; s2 += (double)I * I;
  }
  for (int o = 32; o; o >>= 1) { s += __shfl_down(s, o, 64); s2 += __shfl_down(s2, o, 64); }
  __syncthreads();
  if (lane == 0) { dred[wv] = s; dred2[wv] = s2; }
  __syncthreads();
  if (tid == 0) {
    double t1 = 0, t2 = 0;
    for (int i = 0; i < 16; i++) { t1 += dred[i]; t2 += dred2[i]; }
    bcast[0] = (float)(t1 / N);
    bcast[1] = (float)sqrt((t2 - t1 * t1 / N) / (N - 1));
    sPrefix = 0u; sRank = (N - 1) / 2;
  }
  __syncthreads();
  float meanI = bcast[0], stdI = bcast[1];

  float sv[4]; unsigned ab[4];
  #pragma unroll
  for (int q = 0; q < 4; q++) {
    float sval = (il[q] - meanI) / (stdI + EPSF);
    sv[q] = sval;
    ab[q] = __float_as_uint(fabsf(sval));
  }

  // --- radix select rank-2047 of |s| bit patterns (parallel bucket find) ---
  for (int p = 3; p >= 0; p--) {
    if (tid < 256) hist[tid] = 0;
    __syncthreads();
    unsigned pre = sPrefix;
    int rk = sRank;
    int sh = p * 8;
    unsigned mHi = (p == 3) ? 0u : (0xFFFFFFFFu << (sh + 8));
    #pragma unroll
    for (int q = 0; q < 4; q++)
      if ((ab[q] & mHi) == pre) atomicAdd(&hist[(ab[q] >> sh) & 255], 1);
    __syncthreads();
    int v = (tid < 256) ? hist[tid] : 0;
    int inc = v;
    #pragma unroll
    for (int o = 1; o < 64; o <<= 1) { int u = __shfl_up(inc, o, 64); if (lane >= o) inc += u; }
    if (lane == 63) wsum[wv] = inc;
    __syncthreads();
    if (tid < 16) {
      int t = wsum[tid];
      #pragma unroll
      for (int o = 1; o < 16; o <<= 1) { int u = __shfl_up(t, o, 64); if (tid >= o) t += u; }
      wsum[tid] = t;
    }
    __syncthreads();
    int incl = (wv ? wsum[wv - 1] : 0) + inc;
    int E = incl - v;
    if (tid < 256 && v && rk >= E && rk < E + v) {
      sPrefix = pre | ((unsigned)tid << sh);
      sRank = rk - E;
    }
    __syncthreads();
  }
  float med = __uint_as_float(sPrefix);

  // --- mask (strict |s| > med, bit-exact) + stable compaction (wave scan) ---
  int msk[4], loc[4]; int tot = 0;
  #pragma unroll
  for (int q = 0; q < 4; q++) {
    bool m = fabsf(sv[q]) > med;
    msk[q] = m; loc[q] = tot; tot += (int)m;
  }
  int inc = tot;
  #pragma unroll
  for (int o = 1; o < 64; o <<= 1) { int u = __shfl_up(inc, o, 64); if (lane >= o) inc += u; }
  if (lane == 63) wsum[wv] = inc;
  __syncthreads();
  if (tid < 16) {
    int t = wsum[tid];
    #pragma unroll
    for (int o = 1; o < 16; o <<= 1) { int u = __shfl_up(t, o, 64); if (tid >= o) t += u; }
    wsum[tid] = t;
  }
  __syncthreads();
  int nA = wsum[15];
  int base = (wv ? wsum[wv - 1] : 0) + inc - tot;
  int midl = nA >> 1;
  #pragma unroll
  for (int q = 0; q < 4; q++) {
    int i = tid * 4 + q;
    int r = base + loc[q];
    if (msk[q]) {
      if (r < midl) ws->A1idx[r] = i; else ws->A2idx[r - midl] = i;
    } else {
      ws->Bidx[i - r] = i;
    }
  }
  if (tid == 0) { ws->n_A = nA; ws->mid = midl; ws->n2 = nA - midl; ws->n_B = N - nA; }
}

// gather selected rows into packed, contiguous f16 hi/lo planes
// blocks [0,2048): A1 rows; [2048,4096): A2 rows
__global__ __launch_bounds__(256) void k_pack(const float* __restrict__ x,
                                              f16* __restrict__ PAhi, f16* __restrict__ PAlo,
                                              f16* __restrict__ PBhi, f16* __restrict__ PBlo,
                                              WS* ws) {
  int b = blockIdx.x, t = threadIdx.x;
  const float* src;
  f16 *dh, *dl;
  if (b < 2048) {
    if (b >= ws->mid) return;
    src = x + (size_t)ws->A1idx[b] * D;
    dh = PAhi + (size_t)b * D; dl = PAlo + (size_t)b * D;
  } else {
    int j = b - 2048;
    if (j >= ws->n2) return;
    src = x + (size_t)ws->A2idx[j] * D;
    dh = PBhi + (size_t)j * D; dl = PBlo + (size_t)j * D;
  }
  float4 v = ((const float4*)src)[t];
  float vv[4] = {v.x, v.y, v.z, v.w};
  f16x4 h, l;
  #pragma unroll
  for (int q = 0; q < 4; q++) {
    f16 hq = (f16)vv[q];
    h[q] = hq;
    l[q] = (f16)(vv[q] - (float)hq);
  }
  *(f16x4*)(dh + t * 4) = h;
  *(f16x4*)(dl + t * 4) = l;
}

// f16x3 MFMA sim-GEMM on PACKED planes (coalesced staging) + per-row argmax
__global__ __launch_bounds__(256) void k_gemm(const f16* __restrict__ PAhi,
                                              const f16* __restrict__ PAlo,
                                              const f16* __restrict__ PBhi,
                                              const f16* __restrict__ PBlo, WS* ws) {
  const int mid = ws->mid, n2 = ws->n2;
  // XCD-aware remap: xcd owns a 4-wide bj strip -> B panel stays in its L2
  int L = blockIdx.x;
  int local = L >> 3;
  int bj = ((L & 7) << 2) | (local >> 5);
  int bi = local & 31;
  if (bi * 64 >= mid || bj * 64 >= n2) return;

  __shared__ f16 lds[2][4][64 * 64];  // [buf][Ahi,Alo,Bhi,Blo][row*64+k], 64 KiB

  const int tid = threadIdx.x;
  const int lane = tid & 63;
  const int wid = tid >> 6;
  const int wr = wid >> 1, wc = wid & 1;

  // staging: wave wid owns plane wid; lane address is LINEAR in LDS order.
  // LDS slot (row_local, g) holds source granule g ^ (row_local & 7);
  // src_g = (lane&7) ^ (lane>>3) is constant per lane.
  const f16* plane = (wid == 0) ? PAhi : (wid == 1) ? PAlo : (wid == 2) ? PBhi : PBlo;
  const int pbase = (wid < 2) ? bi * 64 : bj * 64;
  const int pmax = ((wid < 2) ? mid : n2) - 1;
  const int src_g = (lane & 7) ^ (lane >> 3);
  const char* rp[8];
  #pragma unroll
  for (int i = 0; i < 8; i++) {
    int row = pbase + i * 8 + (lane >> 3);
    if (row > pmax) row = pmax;
    rp[i] = (const char*)(plane + (size_t)row * D) + src_g * 16;
  }

  f16x8 pr[8];
  auto LOAD = [&](int t) {
    #pragma unroll
    for (int i = 0; i < 8; i++) pr[i] = *(const f16x8*)(rp[i] + t * 128);
  };
  auto STORE = [&](int buf) {
    #pragma unroll
    for (int i = 0; i < 8; i++) *(f16x8*)&lds[buf][wid][i * 512 + lane * 8] = pr[i];
  };

  const int colg = lane & 15, rowg = lane >> 4;
  const int ma0 = wr * 32 + colg, ma1 = ma0 + 16;
  const int mb0 = wc * 32 + colg, mb1 = mb0 + 16;

  f32x4 zero = {0.f, 0.f, 0.f, 0.f};
  f32x4 acc[2][2];
  acc[0][0] = zero; acc[0][1] = zero; acc[1][0] = zero; acc[1][1] = zero;

#define FRAG(buf, t4, row, g) \
  (*(const f16x8*)&lds[buf][t4][(row) * 64 + ((((g) ^ ((row) & 7))) * 8)])

  LOAD(0);
  STORE(0);
  __syncthreads();
  for (int t16 = 0; t16 < 16; t16++) {
    int buf = t16 & 1;
    if (t16 < 15) LOAD(t16 + 1);  // in flight during MFMAs below
    #pragma unroll
    for (int ks = 0; ks < 2; ks++) {
      int gk = ks * 4 + rowg;
      f16x8 ah0 = FRAG(buf, 0, ma0, gk), ah1 = FRAG(buf, 0, ma1, gk);
      f16x8 al0 = FRAG(buf, 1, ma0, gk), al1 = FRAG(buf, 1, ma1, gk);
      f16x8 bh0 = FRAG(buf, 2, mb0, gk), bh1 = FRAG(buf, 2, mb1, gk);
      f16x8 bl0 = FRAG(buf, 3, mb0, gk), bl1 = FRAG(buf, 3, mb1, gk);
      acc[0][0] = __builtin_amdgcn_mfma_f32_16x16x32_f16(ah0, bh0, acc[0][0], 0, 0, 0);
      acc[0][0] = __builtin_amdgcn_mfma_f32_16x16x32_f16(ah0, bl0, acc[0][0], 0, 0, 0);
      acc[0][0] = __builtin_amdgcn_mfma_f32_16x16x32_f16(al0, bh0, acc[0][0], 0, 0, 0);
      acc[0][1] = __builtin_amdgcn_mfma_f32_16x16x32_f16(ah0, bh1, acc[0][1], 0, 0, 0);
      acc[0][1] = __builtin_amdgcn_mfma_f32_16x16x32_f16(ah0, bl1, acc[0][1], 0, 0, 0);
      acc[0][1] = __builtin_amdgcn_mfma_f32_16x16x32_f16(al0, bh1, acc[0][1], 0, 0, 0);
      acc[1][0] = __builtin_amdgcn_mfma_f32_16x16x32_f16(ah1, bh0, acc[1][0], 0, 0, 0);
      acc[1][0] = __builtin_amdgcn_mfma_f32_16x16x32_f16(ah1, bl0, acc[1][0], 0, 0, 0);
      acc[1][0] = __builtin_amdgcn_mfma_f32_16x16x32_f16(al1, bh0, acc[1][0], 0, 0, 0);
      acc[1][1] = __builtin_amdgcn_mfma_f32_16x16x32_f16(ah1, bh1, acc[1][1], 0, 0, 0);
      acc[1][1] = __builtin_amdgcn_mfma_f32_16x16x32_f16(ah1, bl1, acc[1][1], 0, 0, 0);
      acc[1][1] = __builtin_amdgcn_mfma_f32_16x16x32_f16(al1, bh1, acc[1][1], 0, 0, 0);
    }
    if (t16 < 15) {
      __syncthreads();
      STORE(buf ^ 1);
      __syncthreads();
    }
  }
#undef FRAG

  // epilogue: per-row argmax. C layout: col=lane&15, row=(lane>>4)*4+reg.
  #pragma unroll
  for (int mi = 0; mi < 2; mi++) {
    #pragma unroll
    for (int i = 0; i < 4; i++) {
      int grow = bi * 64 + wr * 32 + mi * 16 + rowg * 4 + i;
      u64 key = 0;
      #pragma unroll
      for (int ni = 0; ni < 2; ni++) {
        int gcol = bj * 64 + wc * 32 + ni * 16 + colg;
        if (gcol < n2) {
          u64 k2 = packKey(acc[mi][ni][i], gcol);
          if (k2 > key) key = k2;
        }
      }
      #pragma unroll
      for (int m = 8; m; m >>= 1) {
        u64 o = (u64)__shfl_xor((long long)key, m, 64);
        if (o > key) key = o;
      }
      if (colg == 0 && grow < mid && key) atomicMax(&ws->bestKey[grow], key);
    }
  }
}

// decode matches + residual compaction (fused, single block, wave scan)
__global__ __launch_bounds__(1024) void k_match(WS* ws) {
  __shared__ int flag[N];
  __shared__ int wsum[16];
  int tid = threadIdx.x;
  int lane = tid & 63, wv = tid >> 6;
  int mid = ws->mid, n2 = ws->n2;
  #pragma unroll
  for (int q = 0; q < 4; q++) flag[tid * 4 + q] = 0;
  __syncthreads();
  #pragma unroll
  for (int q = 0; q < 2; q++) {
    int r = tid + q * 1024;
    if (r < mid) {
      int j = (int)(~(unsigned)(ws->bestKey[r] & 0xffffffffull));
      ws->matches[r] = j;
      flag[j] = 1;  // benign race: same value
    }
  }
  __syncthreads();
  int v[4], loc[4]; int tot = 0;
  #pragma unroll
  for (int q = 0; q < 4; q++) {
    int j = tid * 4 + q;
    bool val = (j < n2) && (flag[j] == 0);
    v[q] = val; loc[q] = tot; tot += (int)val;
  }
  int inc = tot;
  #pragma unroll
  for (int o = 1; o < 64; o <<= 1) { int u = __shfl_up(inc, o, 64); if (lane >= o) inc += u; }
  if (lane == 63) wsum[wv] = inc;
  __syncthreads();
  if (tid < 16) {
    int t = wsum[tid];
    #pragma unroll
    for (int o = 1; o < 16; o <<= 1) { int u = __shfl_up(t, o, 64); if (tid >= o) t += u; }
    wsum[tid] = t;
  }
  __syncthreads();
  int base = (wv ? wsum[wv - 1] : 0) + inc - tot;
  #pragma unroll
  for (int q = 0; q < 4; q++)
    if (v[q]) ws->residIdx[base + loc[q]] = ws->A2idx[tid * 4 + q];
  if (tid == 0) ws->n_resid = wsum[15];
}

// one block per output row (out rows [0,N), residual rows [N,2N))
__global__ __launch_bounds__(256) void k_write(const float* __restrict__ x,
                                               float* __restrict__ out, WS* ws) {
  int r = blockIdx.x;
  int t = threadIdx.x;
  int n_B = ws->n_B, mid = ws->mid, n_resid = ws->n_resid;
  float4 res = make_float4(0.f, 0.f, 0.f, 0.f);
  if (r < N) {
    if (r < n_B) {
      res = ((const float4*)(x + (size_t)ws->Bidx[r] * D))[t];
    } else if (r < n_B + mid) {
      int m = r - n_B;
      float4 v1 = ((const float4*)(x + (size_t)ws->A1idx[m] * D))[t];
      float4 v2 = ((const float4*)(x + (size_t)ws->A2idx[ws->matches[m]] * D))[t];
      res = make_float4(0.5f * (v1.x + v2.x), 0.5f * (v1.y + v2.y),
                        0.5f * (v1.z + v2.z), 0.5f * (v1.w + v2.w));
    }
  } else {
    int k = r - N;
    if (k < n_resid) {
      res = ((const float4*)(x + (size_t)ws->residIdx[k] * D))[t];
    }
  }
  ((float4*)(out + (size_t)r * D))[t] = res;
}

extern "C" void kernel_launch(void* const* d_in, const int* in_sizes, int n_in,
                              void* d_out, int out_size, void* d_ws, size_t ws_size,
                              hipStream_t stream) {
  const float* x = (const float*)d_in[0];
  const float* attn = (const float*)d_in[1];
  float* out = (float*)d_out;
  WS* ws = (WS*)d_ws;
  // d_out (33.5 MB) doubles as scratch for the packed f16 planes (16 MB);
  // k_write fully overwrites it afterwards (stream-ordered, deterministic).
  f16* PAhi = (f16*)d_out;
  f16* PAlo = PAhi + (size_t)2048 * D;
  f16* PBhi = PAlo + (size_t)2048 * D;
  f16* PBlo = PBhi + (size_t)2048 * D;

  k_prep<<<N, 256, 0, stream>>>(x, ws);
  k_mask<<<1, 1024, 0, stream>>>(attn, ws);
  k_pack<<<4096, 256, 0, stream>>>(x, PAhi, PAlo, PBhi, PBlo, ws);
  k_gemm<<<1024, 256, 0, stream>>>(PAhi, PAlo, PBhi, PBlo, ws);
  k_match<<<1, 1024, 0, stream>>>(ws);
  k_write<<<2 * N, 256, 0, stream>>>(x, out, ws);
}

// Round 7
// 58.768 us; speedup vs baseline: 1.2600x; 1.0901x over previous
//
#include <hip/hip_runtime.h>

#define N 4096
#define D 1024
#define EPSF 1e-6f

typedef _Float16 f16;
typedef f16 f16x8 __attribute__((ext_vector_type(8)));
typedef float f32x4 __attribute__((ext_vector_type(4)));
typedef unsigned long long u64;

#define PLANE ((size_t)2048 * 1024)  // f16 elements per packed plane

struct WS {
  int n_A, mid, n2, n_B, n_resid, pad[3];
  float a[N];
  float diag[N];
  int A1idx[N];
  int A2idx[N];
  int Bidx[N];
  int matches[N];
  int residIdx[N];
  u64 bestKey[2048];
};

__device__ __forceinline__ u64 packKey(float v, int j) {
  unsigned u = __float_as_uint(v);
  unsigned m = (u & 0x80000000u) ? ~u : (u | 0x80000000u);
  return ((u64)m << 32) | (unsigned)(~(unsigned)j);
}

// row means of x + attn diagonal gather (spread across grid, not serial)
__global__ __launch_bounds__(256) void k_prep(const float* __restrict__ x,
                                              const float* __restrict__ attn, WS* ws) {
  int row = blockIdx.x;
  int t = threadIdx.x;
  float4 v = ((const float4*)(x + (size_t)row * D))[t];
  float sm = v.x + v.y + v.z + v.w;
  for (int o = 32; o; o >>= 1) sm += __shfl_down(sm, o, 64);
  __shared__ float w[4];
  if ((t & 63) == 0) w[t >> 6] = sm;
  __syncthreads();
  if (t == 0) {
    ws->a[row] = (w[0] + w[1] + w[2] + w[3]) * (1.0f / D);
    ws->diag[row] = attn[(size_t)row * N + row];
  }
}

// fused: stats(a) -> z -> Il -> stats(Il) -> s -> radix-select median(|s|)
//        -> mask + stable compaction + bestKey zero-init
__global__ __launch_bounds__(1024) void k_mask(WS* ws) {
  __shared__ double dred[16], dred2[16];
  __shared__ float bcast[2];
  __shared__ int hist[256];
  __shared__ int wsum[16];
  __shared__ unsigned sPrefix;
  __shared__ int sRank;
  int tid = threadIdx.x;
  int lane = tid & 63, wv = tid >> 6;

  ws->bestKey[tid] = 0ull;
  ws->bestKey[tid + 1024] = 0ull;

  // --- stats of a ---
  float av[4];
  double s = 0.0, s2 = 0.0;
  #pragma unroll
  for (int q = 0; q < 4; q++) {
    float f = ws->a[tid * 4 + q];
    av[q] = f; s += f; s2 += (double)f * f;
  }
  for (int o = 32; o; o >>= 1) { s += __shfl_down(s, o, 64); s2 += __shfl_down(s2, o, 64); }
  if (lane == 0) { dred[wv] = s; dred2[wv] = s2; }
  __syncthreads();
  if (tid == 0) {
    double t1 = 0, t2 = 0;
    for (int i = 0; i < 16; i++) { t1 += dred[i]; t2 += dred2[i]; }
    bcast[0] = (float)(t1 / N);
    bcast[1] = (float)sqrt((t2 - t1 * t1 / N) / (N - 1));
  }
  __syncthreads();
  float meanA = bcast[0], stdA = bcast[1];

  // --- Il = z^2 * diag(attn), plus its stats ---
  float il[4];
  s = 0.0; s2 = 0.0;
  #pragma unroll
  for (int q = 0; q < 4; q++) {
    int i = tid * 4 + q;
    float z = (av[q] - meanA) / (stdA + EPSF);
    float I = z * z * ws->diag[i];
    il[q] = I; s += I; s2 += (double)I * I;
  }
  for (int o = 32; o; o >>= 1) { s += __shfl_down(s, o, 64); s2 += __shfl_down(s2, o, 64); }
  __syncthreads();
  if (lane == 0) { dred[wv] = s; dred2[wv] = s2; }
  __syncthreads();
  if (tid == 0) {
    double t1 = 0, t2 = 0;
    for (int i = 0; i < 16; i++) { t1 += dred[i]; t2 += dred2[i]; }
    bcast[0] = (float)(t1 / N);
    bcast[1] = (float)sqrt((t2 - t1 * t1 / N) / (N - 1));
    sPrefix = 0u; sRank = (N - 1) / 2;
  }
  __syncthreads();
  float meanI = bcast[0], stdI = bcast[1];

  float sv[4]; unsigned ab[4];
  #pragma unroll
  for (int q = 0; q < 4; q++) {
    float sval = (il[q] - meanI) / (stdI + EPSF);
    sv[q] = sval;
    ab[q] = __float_as_uint(fabsf(sval));
  }

  // --- radix select rank-2047 of |s| bit patterns (parallel bucket find) ---
  for (int p = 3; p >= 0; p--) {
    if (tid < 256) hist[tid] = 0;
    __syncthreads();
    unsigned pre = sPrefix;
    int rk = sRank;
    int sh = p * 8;
    unsigned mHi = (p == 3) ? 0u : (0xFFFFFFFFu << (sh + 8));
    #pragma unroll
    for (int q = 0; q < 4; q++)
      if ((ab[q] & mHi) == pre) atomicAdd(&hist[(ab[q] >> sh) & 255], 1);
    __syncthreads();
    int v = (tid < 256) ? hist[tid] : 0;
    int inc = v;
    #pragma unroll
    for (int o = 1; o < 64; o <<= 1) { int u = __shfl_up(inc, o, 64); if (lane >= o) inc += u; }
    if (lane == 63) wsum[wv] = inc;
    __syncthreads();
    if (tid < 16) {
      int t = wsum[tid];
      #pragma unroll
      for (int o = 1; o < 16; o <<= 1) { int u = __shfl_up(t, o, 64); if (tid >= o) t += u; }
      wsum[tid] = t;
    }
    __syncthreads();
    int incl = (wv ? wsum[wv - 1] : 0) + inc;
    int E = incl - v;
    if (tid < 256 && v && rk >= E && rk < E + v) {
      sPrefix = pre | ((unsigned)tid << sh);
      sRank = rk - E;
    }
    __syncthreads();
  }
  float med = __uint_as_float(sPrefix);

  // --- mask (strict |s| > med, bit-exact) + stable compaction (wave scan) ---
  int msk[4], loc[4]; int tot = 0;
  #pragma unroll
  for (int q = 0; q < 4; q++) {
    bool m = fabsf(sv[q]) > med;
    msk[q] = m; loc[q] = tot; tot += (int)m;
  }
  int inc = tot;
  #pragma unroll
  for (int o = 1; o < 64; o <<= 1) { int u = __shfl_up(inc, o, 64); if (lane >= o) inc += u; }
  if (lane == 63) wsum[wv] = inc;
  __syncthreads();
  if (tid < 16) {
    int t = wsum[tid];
    #pragma unroll
    for (int o = 1; o < 16; o <<= 1) { int u = __shfl_up(t, o, 64); if (tid >= o) t += u; }
    wsum[tid] = t;
  }
  __syncthreads();
  int nA = wsum[15];
  int base = (wv ? wsum[wv - 1] : 0) + inc - tot;
  int midl = nA >> 1;
  #pragma unroll
  for (int q = 0; q < 4; q++) {
    int i = tid * 4 + q;
    int r = base + loc[q];
    if (msk[q]) {
      if (r < midl) ws->A1idx[r] = i; else ws->A2idx[r - midl] = i;
    } else {
      ws->Bidx[i - r] = i;
    }
  }
  if (tid == 0) { ws->n_A = nA; ws->mid = midl; ws->n2 = nA - midl; ws->n_B = N - nA; }
}

// gather selected rows -> f16 hi/lo planes in TILED layout:
// plane = [rowTile][kTile][tile of 64 rows x 64 k, 8KB contiguous],
// with the LDS XOR-granule swizzle baked in: within a tile, row rl's source
// granule gl (8 f16) is stored at f16-offset rl*64 + ((gl ^ (rl&7)) * 8).
// blocks [0,2048): A1 rows; [2048,4096): A2 rows. 128 threads = 1 row.
__global__ __launch_bounds__(128) void k_pack(const float* __restrict__ x,
                                              f16* __restrict__ PAhi, f16* __restrict__ PAlo,
                                              f16* __restrict__ PBhi, f16* __restrict__ PBlo,
                                              WS* ws) {
  int b = blockIdx.x, t = threadIdx.x;
  const float* src;
  f16 *dh, *dl;
  int j;
  if (b < 2048) {
    if (b >= ws->mid) return;
    j = b;
    src = x + (size_t)ws->A1idx[b] * D;
    dh = PAhi; dl = PAlo;
  } else {
    j = b - 2048;
    if (j >= ws->n2) return;
    src = x + (size_t)ws->A2idx[j] * D;
    dh = PBhi; dl = PBlo;
  }
  // thread t owns source f32 [t*8, t*8+8) = k-tile t>>3, granule t&7
  float4 v0 = ((const float4*)src)[t * 2];
  float4 v1 = ((const float4*)src)[t * 2 + 1];
  float vv[8] = {v0.x, v0.y, v0.z, v0.w, v1.x, v1.y, v1.z, v1.w};
  f16x8 h, l;
  #pragma unroll
  for (int q = 0; q < 8; q++) {
    f16 hq = (f16)vv[q];
    h[q] = hq;
    l[q] = (f16)(vv[q] - (float)hq);
  }
  int rt = j >> 6, rl = j & 63;
  int kt = t >> 3, gl = t & 7;
  size_t off = ((size_t)(rt * 16 + kt) << 12) + rl * 64 + ((gl ^ (rl & 7)) * 8);
  *(f16x8*)(dh + off) = h;
  *(f16x8*)(dl + off) = l;
}

// f16x3 MFMA sim-GEMM on TILED packed planes (fully coalesced staging:
// every load instruction = 1KB contiguous) + per-row argmax
__global__ __launch_bounds__(256) void k_gemm(const f16* __restrict__ PAhi,
                                              const f16* __restrict__ PAlo,
                                              const f16* __restrict__ PBhi,
                                              const f16* __restrict__ PBlo, WS* ws) {
  const int mid = ws->mid, n2 = ws->n2;
  // 256 blocks exactly; xcd = L&7 owns bj pair {2*xcd, 2*xcd+1}
  int L = blockIdx.x;
  int local = L >> 3;
  int bj = ((L & 7) << 1) | (local >> 4);
  int bi = local & 15;
  if (bi * 64 >= mid || bj * 64 >= n2) return;

  __shared__ f16 lds[2][4][64 * 64];  // [buf][Ahi,Alo,Bhi,Blo][tile], 64 KiB

  const int tid = threadIdx.x;
  const int lane = tid & 63;
  const int wid = tid >> 6;
  const int wr = wid >> 1, wc = wid & 1;

  // wave wid stages its plane; tiles are contiguous 8KB, copy is linear
  const f16* plane = (wid == 0) ? PAhi : (wid == 1) ? PAlo : (wid == 2) ? PBhi : PBlo;
  const int ptile = (wid < 2) ? bi : bj;

  f16x8 pr[8];
  auto LOAD = [&](int t) {
    const f16* tb = plane + ((size_t)((ptile << 4) + t) << 12);
    #pragma unroll
    for (int i = 0; i < 8; i++) pr[i] = *(const f16x8*)(tb + i * 512 + lane * 8);
  };
  auto STORE = [&](int buf) {
    #pragma unroll
    for (int i = 0; i < 8; i++) *(f16x8*)&lds[buf][wid][i * 512 + lane * 8] = pr[i];
  };

  const int colg = lane & 15, rowg = lane >> 4;
  const int ma0 = wr * 32 + colg, ma1 = ma0 + 16;
  const int mb0 = wc * 32 + colg, mb1 = mb0 + 16;

  f32x4 zero = {0.f, 0.f, 0.f, 0.f};
  f32x4 acc[2][2];
  acc[0][0] = zero; acc[0][1] = zero; acc[1][0] = zero; acc[1][1] = zero;

#define FRAG(buf, t4, row, g) \
  (*(const f16x8*)&lds[buf][t4][(row) * 64 + ((((g) ^ ((row) & 7))) * 8)])

  LOAD(0);
  STORE(0);
  __syncthreads();
  for (int t16 = 0; t16 < 16; t16++) {
    int buf = t16 & 1;
    if (t16 < 15) LOAD(t16 + 1);  // in flight during MFMAs below
    #pragma unroll
    for (int ks = 0; ks < 2; ks++) {
      int gk = ks * 4 + rowg;
      f16x8 ah0 = FRAG(buf, 0, ma0, gk), ah1 = FRAG(buf, 0, ma1, gk);
      f16x8 al0 = FRAG(buf, 1, ma0, gk), al1 = FRAG(buf, 1, ma1, gk);
      f16x8 bh0 = FRAG(buf, 2, mb0, gk), bh1 = FRAG(buf, 2, mb1, gk);
      f16x8 bl0 = FRAG(buf, 3, mb0, gk), bl1 = FRAG(buf, 3, mb1, gk);
      acc[0][0] = __builtin_amdgcn_mfma_f32_16x16x32_f16(ah0, bh0, acc[0][0], 0, 0, 0);
      acc[0][0] = __builtin_amdgcn_mfma_f32_16x16x32_f16(ah0, bl0, acc[0][0], 0, 0, 0);
      acc[0][0] = __builtin_amdgcn_mfma_f32_16x16x32_f16(al0, bh0, acc[0][0], 0, 0, 0);
      acc[0][1] = __builtin_amdgcn_mfma_f32_16x16x32_f16(ah0, bh1, acc[0][1], 0, 0, 0);
      acc[0][1] = __builtin_amdgcn_mfma_f32_16x16x32_f16(ah0, bl1, acc[0][1], 0, 0, 0);
      acc[0][1] = __builtin_amdgcn_mfma_f32_16x16x32_f16(al0, bh1, acc[0][1], 0, 0, 0);
      acc[1][0] = __builtin_amdgcn_mfma_f32_16x16x32_f16(ah1, bh0, acc[1][0], 0, 0, 0);
      acc[1][0] = __builtin_amdgcn_mfma_f32_16x16x32_f16(ah1, bl0, acc[1][0], 0, 0, 0);
      acc[1][0] = __builtin_amdgcn_mfma_f32_16x16x32_f16(al1, bh0, acc[1][0], 0, 0, 0);
      acc[1][1] = __builtin_amdgcn_mfma_f32_16x16x32_f16(ah1, bh1, acc[1][1], 0, 0, 0);
      acc[1][1] = __builtin_amdgcn_mfma_f32_16x16x32_f16(ah1, bl1, acc[1][1], 0, 0, 0);
      acc[1][1] = __builtin_amdgcn_mfma_f32_16x16x32_f16(al1, bh1, acc[1][1], 0, 0, 0);
    }
    if (t16 < 15) {
      __syncthreads();
      STORE(buf ^ 1);
      __syncthreads();
    }
  }
#undef FRAG

  // epilogue: per-row argmax. C layout: col=lane&15, row=(lane>>4)*4+reg.
  #pragma unroll
  for (int mi = 0; mi < 2; mi++) {
    #pragma unroll
    for (int i = 0; i < 4; i++) {
      int grow = bi * 64 + wr * 32 + mi * 16 + rowg * 4 + i;
      u64 key = 0;
      #pragma unroll
      for (int ni = 0; ni < 2; ni++) {
        int gcol = bj * 64 + wc * 32 + ni * 16 + colg;
        if (gcol < n2) {
          u64 k2 = packKey(acc[mi][ni][i], gcol);
          if (k2 > key) key = k2;
        }
      }
      #pragma unroll
      for (int m = 8; m; m >>= 1) {
        u64 o = (u64)__shfl_xor((long long)key, m, 64);
        if (o > key) key = o;
      }
      if (colg == 0 && grow < mid && key) atomicMax(&ws->bestKey[grow], key);
    }
  }
}

// decode matches + residual compaction (fused, single block, wave scan)
__global__ __launch_bounds__(1024) void k_match(WS* ws) {
  __shared__ int flag[N];
  __shared__ int wsum[16];
  int tid = threadIdx.x;
  int lane = tid & 63, wv = tid >> 6;
  int mid = ws->mid, n2 = ws->n2;
  #pragma unroll
  for (int q = 0; q < 4; q++) flag[tid * 4 + q] = 0;
  __syncthreads();
  #pragma unroll
  for (int q = 0; q < 2; q++) {
    int r = tid + q * 1024;
    if (r < mid) {
      int j = (int)(~(unsigned)(ws->bestKey[r] & 0xffffffffull));
      ws->matches[r] = j;
      flag[j] = 1;  // benign race: same value
    }
  }
  __syncthreads();
  int v[4], loc[4]; int tot = 0;
  #pragma unroll
  for (int q = 0; q < 4; q++) {
    int j = tid * 4 + q;
    bool val = (j < n2) && (flag[j] == 0);
    v[q] = val; loc[q] = tot; tot += (int)val;
  }
  int inc = tot;
  #pragma unroll
  for (int o = 1; o < 64; o <<= 1) { int u = __shfl_up(inc, o, 64); if (lane >= o) inc += u; }
  if (lane == 63) wsum[wv] = inc;
  __syncthreads();
  if (tid < 16) {
    int t = wsum[tid];
    #pragma unroll
    for (int o = 1; o < 16; o <<= 1) { int u = __shfl_up(t, o, 64); if (tid >= o) t += u; }
    wsum[tid] = t;
  }
  __syncthreads();
  int base = (wv ? wsum[wv - 1] : 0) + inc - tot;
  #pragma unroll
  for (int q = 0; q < 4; q++)
    if (v[q]) ws->residIdx[base + loc[q]] = ws->A2idx[tid * 4 + q];
  if (tid == 0) ws->n_resid = wsum[15];
}

// one block per output row (out rows [0,N), residual rows [N,2N))
__global__ __launch_bounds__(256) void k_write(const float* __restrict__ x,
                                               float* __restrict__ out, WS* ws) {
  int r = blockIdx.x;
  int t = threadIdx.x;
  int n_B = ws->n_B, mid = ws->mid, n_resid = ws->n_resid;
  float4 res = make_float4(0.f, 0.f, 0.f, 0.f);
  if (r < N) {
    if (r < n_B) {
      res = ((const float4*)(x + (size_t)ws->Bidx[r] * D))[t];
    } else if (r < n_B + mid) {
      int m = r - n_B;
      float4 v1 = ((const float4*)(x + (size_t)ws->A1idx[m] * D))[t];
      float4 v2 = ((const float4*)(x + (size_t)ws->A2idx[ws->matches[m]] * D))[t];
      res = make_float4(0.5f * (v1.x + v2.x), 0.5f * (v1.y + v2.y),
                        0.5f * (v1.z + v2.z), 0.5f * (v1.w + v2.w));
    }
  } else {
    int k = r - N;
    if (k < n_resid) {
      res = ((const float4*)(x + (size_t)ws->residIdx[k] * D))[t];
    }
  }
  ((float4*)(out + (size_t)r * D))[t] = res;
}

extern "C" void kernel_launch(void* const* d_in, const int* in_sizes, int n_in,
                              void* d_out, int out_size, void* d_ws, size_t ws_size,
                              hipStream_t stream) {
  const float* x = (const float*)d_in[0];
  const float* attn = (const float*)d_in[1];
  float* out = (float*)d_out;
  WS* ws = (WS*)d_ws;
  // d_out (33.5 MB) doubles as scratch for the tiled packed f16 planes (16 MB);
  // k_write fully overwrites it afterwards (stream-ordered, deterministic).
  f16* PAhi = (f16*)d_out;
  f16* PAlo = PAhi + PLANE;
  f16* PBhi = PAlo + PLANE;
  f16* PBlo = PBhi + PLANE;

  k_prep<<<N, 256, 0, stream>>>(x, attn, ws);
  k_mask<<<1, 1024, 0, stream>>>(ws);
  k_pack<<<4096, 128, 0, stream>>>(x, PAhi, PAlo, PBhi, PBlo, ws);
  k_gemm<<<256, 256, 0, stream>>>(PAhi, PAlo, PBhi, PBlo, ws);
  k_match<<<1, 1024, 0, stream>>>(ws);
  k_write<<<2 * N, 256, 0, stream>>>(x, out, ws);
}